// Round 11
// baseline (117.480 us; speedup 1.0000x reference)
//
#include <hip/hip_runtime.h>
#include <hip/hip_bf16.h>

// Problem constants
#define SRC    16384     // 128*128 source pixels
#define DCH    64        // channels
#define NCLS   19        // classes
#define NPAIR  (NCLS*DCH)// 1216 (c,d) pairs

// Bare v_exp_f32 (args in [-450,0]; underflow->0 matches reference f32 exp).
#if defined(__has_builtin)
#if __has_builtin(__builtin_amdgcn_exp2f)
#define EXP2F(x) __builtin_amdgcn_exp2f(x)
#else
#define EXP2F(x) __exp2f(x)
#endif
#else
#define EXP2F(x) __exp2f(x)
#endif

// ---------------------------------------------------------------------------
// K1: build per-class compacted lists. Each source pixel covers a 4x4 block
// of the 512x512 label map; cnt_c(s) = #subpixels with label c (0..16).
// Only pixels with cnt_c > 0 enter class c's list as (cnt<<16 | pixel_idx).
// ~42% of (c,pixel) combos have cnt==0 (random labels) -> 0.58x work for K2.
// Rank within block via __ballot + popc (pixel-ordered -> near-coalesced
// gathers in K2); block base via one atomicAdd per (c,block) on lpos[c].
// ---------------------------------------------------------------------------
__global__ __launch_bounds__(256) void hl_build_kernel(
    const int* __restrict__ label, unsigned int* __restrict__ list,
    int* __restrict__ lpos)
{
    int t    = threadIdx.x;
    int s    = blockIdx.x * 256 + t;           // 64 blocks x 256 = 16384
    int lane = t & 63, wv = t >> 6;
    int sy = s >> 7, sx = s & 127;

    const int4* lab4 = (const int4*)label;
    int l[16];
#pragma unroll
    for (int r = 0; r < 4; r++) {
        int4 v = lab4[(4 * sy + r) * 128 + sx];
        l[4 * r + 0] = v.x; l[4 * r + 1] = v.y;
        l[4 * r + 2] = v.z; l[4 * r + 3] = v.w;
    }
    int cc[NCLS];
#pragma unroll
    for (int c = 0; c < NCLS; c++) {
        int n = 0;
#pragma unroll
        for (int j = 0; j < 16; j++) n += (l[j] == c) ? 1 : 0;
        cc[c] = n;
    }

    __shared__ int wsum[4];
    __shared__ int sh_base;
    unsigned long long mlt = (1ull << lane) - 1ull;   // lanes below me

    for (int c = 0; c < NCLS; c++) {
        bool pred = cc[c] > 0;
        unsigned long long b = __ballot(pred);
        int rw = __popcll(b & mlt);            // rank within wave
        if (lane == 0) wsum[wv] = __popcll(b);
        __syncthreads();
        int w0 = wsum[0], w1 = wsum[1], w2 = wsum[2], w3 = wsum[3];
        int wo = (wv > 0 ? w0 : 0) + (wv > 1 ? w1 : 0) + (wv > 2 ? w2 : 0);
        if (t == 0) sh_base = atomicAdd(&lpos[c], w0 + w1 + w2 + w3);
        __syncthreads();
        if (pred)
            list[c * SRC + sh_base + wo + rw] =
                ((unsigned)cc[c] << 16) | (unsigned)s;
        __syncthreads();                        // protect wsum/sh_base reuse
    }
}

// ---------------------------------------------------------------------------
// K2: fused moments + KDE + per-pair loss, list-driven. One 256-thread block
// per (c,d). L = lpos[c] entries (~9.5K), each (cnt<<16|idx).
//   Pass 1: f32 partials of sum cv*x, cv*x^2, cv -> f64 reduce -> mu, istd,
//           n (= sum cv, exact in f32). d==0 block stores ncls[c].
//   Pass 2: 7-bin KDE, bare v_exp_f32 (1/sqrt(2 pi var_s) cancels in the
//           normalization); block reduce; smooth-L1 partial; one f32
//           atomicAdd into psum.
// 2-deep software pipeline: prefetch next list entry and its feature word.
// Gathers are near-coalesced (entries pixel-ordered per block segment).
// ---------------------------------------------------------------------------
__global__ __launch_bounds__(256, 4) void hl_fused_kernel(
    const float* __restrict__ feature, const unsigned int* __restrict__ list,
    const int* __restrict__ lpos, int* __restrict__ ncls,
    float* __restrict__ psum)
{
    int w = blockIdx.x;             // pair 0..1215
    int c = w >> 6, d = w & 63;
    int t = threadIdx.x;
    int wid = t >> 6;

    int L = lpos[c];                // uniform (same address across block)
    const unsigned int* lst = list + c * SRC;
    const float*        fp  = feature + d * SRC;

    // ---- Pass 1: moments --------------------------------------------------
    float f1 = 0.f, f2 = 0.f, nf = 0.f;
    {
        unsigned e0 = (t < L) ? lst[t] : 0u;
        float    x0 = fp[e0 & 0xFFFFu];
        for (int i = t; i < L; i += 256) {
            int in = i + 256;
            unsigned e1 = (in < L) ? lst[in] : 0u;
            float    x1 = fp[e1 & 0xFFFFu];
            float cv = (float)(e0 >> 16);
            float wx = cv * x0;
            f1 += wx;
            f2 = fmaf(wx, x0, f2);
            nf += cv;
            e0 = e1; x0 = x1;
        }
    }
    double s1 = (double)f1, s2 = (double)f2;
#pragma unroll
    for (int o = 32; o > 0; o >>= 1) {
        s1 += __shfl_down(s1, o);
        s2 += __shfl_down(s2, o);
        nf += __shfl_down(nf, o);
    }
    __shared__ double ps1[4], ps2[4];
    __shared__ float  pnf[4];
    __shared__ float  sh_mu, sh_istd;
    __shared__ int    sh_act;
    if ((t & 63) == 0) { ps1[wid] = s1; ps2[wid] = s2; pnf[wid] = nf; }
    __syncthreads();
    if (t == 0) {
        double a = ps1[0] + ps1[1] + ps1[2] + ps1[3];
        double b = ps2[0] + ps2[1] + ps2[2] + ps2[3];
        int    n = (int)(pnf[0] + pnf[1] + pnf[2] + pnf[3]);  // exact integer
        double nsafe = (n > 0) ? (double)n : 1.0;
        double mu  = a / nsafe;
        double var = (b - 2.0 * mu * a + mu * mu * (double)n) / nsafe + 1e-10;
        sh_mu   = (float)mu;
        sh_istd = (float)(1.0 / sqrt(var));
        sh_act  = (n >= 1000);
        if (d == 0) ncls[c] = n;    // plain store; consumed only by K3
    }
    __syncthreads();
    if (!sh_act) return;            // inactive class: contributes 0
    float istd = sh_istd;
    float nm   = -sh_mu * istd;     // u = fma(x, istd, nm)

    // ---- Pass 2: KDE (list + feature row are L1/L2-hot) -------------------
    const float C1 = -18.033688011112042f;   // -12.5 * log2(e)
    float acc[7] = {0.f, 0.f, 0.f, 0.f, 0.f, 0.f, 0.f};
    {
        unsigned e0 = (t < L) ? lst[t] : 0u;
        float    x0 = fp[e0 & 0xFFFFu];
        for (int i = t; i < L; i += 256) {
            int in = i + 256;
            unsigned e1 = (in < L) ? lst[in] : 0u;
            float    x1 = fp[e1 & 0xFFFFu];
            float cv = (float)(e0 >> 16);
            float u  = fmaf(x0, istd, nm);
            float p  = C1 * u;
            float q  = p * u;                // C1*u^2
#pragma unroll
            for (int k = 0; k < 7; k++) {
                float km  = (float)(k - 3);
                float arg = fmaf(p, -2.f * km, q + C1 * km * km);
                acc[k] = fmaf(cv, EXP2F(arg), acc[k]);
            }
            e0 = e1; x0 = x1;
        }
    }

    __shared__ float part[4][7];
#pragma unroll
    for (int j = 0; j < 7; j++) {
        float v = acc[j];
#pragma unroll
        for (int o = 32; o > 0; o >>= 1) v += __shfl_down(v, o);
        if ((t & 63) == 0) part[wid][j] = v;
    }
    __syncthreads();

    if (t == 0) {
        // target: exp(-0.5 k^2)/Z (1/sqrt(2 pi var) cancels in normalization)
        double e[7], z = 0.0;
#pragma unroll
        for (int k = -3; k <= 3; k++) { e[k + 3] = exp(-0.5 * (double)(k * k)); z += e[k + 3]; }

        float hist[7], S = 0.f;
#pragma unroll
        for (int j = 0; j < 7; j++) {
            hist[j] = part[0][j] + part[1][j] + part[2][j] + part[3][j];
            S += hist[j];
        }
        float Ss = fmaxf(S, 1e-30f);
        float ps = 0.f;
#pragma unroll
        for (int j = 0; j < 7; j++) {
            float dd = fabsf(hist[j] / Ss - (float)(e[j] / z));
            ps += (dd < 1.f) ? 0.5f * dd * dd : (dd - 0.5f);
        }
        atomicAdd(psum, ps);        // raw partial; scaled once in K3
    }
}

// ---------------------------------------------------------------------------
// K3: finalize. A = #active classes; out = psum / (448 * A). Writes out
// absolutely (harness-poisoned d_out needs no pre-zero).
// ---------------------------------------------------------------------------
__global__ __launch_bounds__(64) void hl_final_kernel(
    const float* __restrict__ psum, const int* __restrict__ ncls,
    float* __restrict__ out)
{
    if (threadIdx.x == 0) {
        int A = 0;
#pragma unroll
        for (int i = 0; i < NCLS; i++) A += (ncls[i] >= 1000) ? 1 : 0;
        out[0] = (A > 0) ? psum[0] / (448.0f * (float)A) : 0.0f;
    }
}

// ---------------------------------------------------------------------------
extern "C" void kernel_launch(void* const* d_in, const int* in_sizes, int n_in,
                              void* d_out, int out_size, void* d_ws, size_t ws_size,
                              hipStream_t stream)
{
    const float* feature = (const float*)d_in[0];   // [1,64,128,128] fp32
    const int*   label   = (const int*)d_in[1];     // [1,1,512,512]  int32
    float*       out     = (float*)d_out;           // scalar fp32

    char* ws = (char*)d_ws;
    unsigned int* list = (unsigned int*)(ws);           // 19*16384*4 = 1245184 B
    int*          lpos = (int*)(ws + 1245184);          // 76 B
    int*          ncls = (int*)(ws + 1245184 + 128);    // 76 B
    float*        psum = (float*)(ws + 1245184 + 256);  // 4 B

    // zero lpos + ncls + psum (one thin node; runs before all kernels)
    hipMemsetAsync(ws + 1245184, 0, 260, stream);
    hl_build_kernel<<<SRC / 256, 256, 0, stream>>>(label, list, lpos);
    hl_fused_kernel<<<NPAIR, 256, 0, stream>>>(feature, list, lpos, ncls, psum);
    hl_final_kernel<<<1, 64, 0, stream>>>(psum, ncls, out);
}

// Round 12
// 87.881 us; speedup vs baseline: 1.3368x; 1.3368x over previous
//
#include <hip/hip_runtime.h>
#include <hip/hip_bf16.h>

// Problem constants
#define SRC    16384     // 128*128 source pixels
#define DCH    64        // channels
#define NCLS   19        // classes
#define NPAIR  (NCLS*DCH)// 1216 (c,d) pairs

// GUARANTEED bare v_exp_f32 via inline asm. Args here are in [-450, 0];
// flush-to-zero on underflow matches the reference's f32 exp behavior.
// (R3-R10 used __has_builtin(__builtin_amdgcn_exp2f) with a silent guarded
// fallback -- cycle accounting at R11 says the guarded path was engaged:
// ~300 cy/wave-pixel measured vs 274 guarded-model / 193 bare-model.)
// CDNA VALU->VALU results are hardware-interlocked; no s_nop required.
__device__ __forceinline__ float exp2_raw(float x)
{
    float r;
    asm("v_exp_f32 %0, %1" : "=v"(r) : "v"(x));
    return r;
}

// ---------------------------------------------------------------------------
// K1: per-source-pixel class counts. Each source pixel covers a 4x4 block of
// the 512x512 label map. cnt[c*SRC + s] = #subpixels with label c (0..16).
// Also zeroes the psum accumulator (K2 atomicAdds into it after the boundary).
// ---------------------------------------------------------------------------
__global__ __launch_bounds__(256) void hl_count_kernel(
    const int* __restrict__ label, unsigned char* __restrict__ cnt,
    float* __restrict__ psum)
{
    if (blockIdx.x == 0 && threadIdx.x == 0) psum[0] = 0.f;
    int s  = blockIdx.x * 256 + threadIdx.x;   // 64 blocks x 256 = 16384
    int sy = s >> 7, sx = s & 127;
    const int4* lab4 = (const int4*)label;
    int l[16];
#pragma unroll
    for (int r = 0; r < 4; r++) {
        int4 v = lab4[(4 * sy + r) * 128 + sx];
        l[4 * r + 0] = v.x; l[4 * r + 1] = v.y;
        l[4 * r + 2] = v.z; l[4 * r + 3] = v.w;
    }
#pragma unroll
    for (int c = 0; c < NCLS; c++) {
        int cc = 0;
#pragma unroll
        for (int j = 0; j < 16; j++) cc += (l[j] == c) ? 1 : 0;
        cnt[c * SRC + s] = (unsigned char)cc;
    }
}

// ---------------------------------------------------------------------------
// K2: fused moments + KDE + per-pair loss. One 256-thread block per (c,d),
// 64 px/thread. mu/var/n of pair (c,d) depend only on this block's own 80 KB
// (feature row d + cnt row c) -> no grid-wide dependency.
//   Pass 1: f32 thread partials -> f64 shuffle/LDS reduce -> mu, istd, n.
//           d==0 block publishes ncls[c] (plain store; read only by K3).
//   Pass 2: 7-bin KDE (bare v_exp_f32 via inline asm; 1/sqrt(2*pi*var_s)
//           cancels in the normalization), block reduce, smooth-L1 vs fixed
//           target, one f32 atomicAdd of the raw partial into psum.
// launch_bounds(256,4): 128-VGPR budget, no spills (R9/R10-verified).
// ---------------------------------------------------------------------------
__global__ __launch_bounds__(256, 4) void hl_fused_kernel(
    const float* __restrict__ feature, const unsigned char* __restrict__ cnt,
    int* __restrict__ ncls, float* __restrict__ psum)
{
    int w = blockIdx.x;             // pair 0..1215
    int c = w >> 6, d = w & 63;
    int t = threadIdx.x;
    int wid = t >> 6;

    const float4*       fp4 = (const float4*)(feature + d * SRC);
    const unsigned int* cpu = (const unsigned int*)(cnt + c * SRC);

    // ---- Pass 1: moments --------------------------------------------------
    float f1 = 0.f, f2 = 0.f;
    int   nc = 0;
#pragma unroll 4
    for (int i = 0; i < 16; i++) {
        int g = i * 256 + t;        // 4096 float4-groups (= 4096 uint groups)
        float4       x  = fp4[g];
        unsigned int cv = cpu[g];
        float xs[4] = {x.x, x.y, x.z, x.w};
        float cf[4] = {(float)(cv & 255u), (float)((cv >> 8) & 255u),
                       (float)((cv >> 16) & 255u), (float)(cv >> 24)};
#pragma unroll
        for (int e = 0; e < 4; e++) {
            float wx = cf[e] * xs[e];
            f1 += wx;
            f2 = fmaf(wx, xs[e], f2);
        }
        nc += (cv & 255u) + ((cv >> 8) & 255u) + ((cv >> 16) & 255u) + (cv >> 24);
    }
    double s1 = (double)f1, s2 = (double)f2;
#pragma unroll
    for (int o = 32; o > 0; o >>= 1) {
        s1 += __shfl_down(s1, o);
        s2 += __shfl_down(s2, o);
        nc += __shfl_down(nc, o);
    }
    __shared__ double ps1[4], ps2[4];
    __shared__ int    pn[4];
    __shared__ float  sh_mu, sh_istd;
    __shared__ int    sh_act;
    if ((t & 63) == 0) { ps1[wid] = s1; ps2[wid] = s2; pn[wid] = nc; }
    __syncthreads();
    if (t == 0) {
        double a = ps1[0] + ps1[1] + ps1[2] + ps1[3];
        double b = ps2[0] + ps2[1] + ps2[2] + ps2[3];
        int    n = pn[0] + pn[1] + pn[2] + pn[3];
        double nsafe = (n > 0) ? (double)n : 1.0;
        double mu  = a / nsafe;
        double var = (b - 2.0 * mu * a + mu * mu * (double)n) / nsafe + 1e-10;
        sh_mu   = (float)mu;
        sh_istd = (float)(1.0 / sqrt(var));
        sh_act  = (n >= 1000);
        if (d == 0) ncls[c] = n;    // plain store; consumed only by K3
    }
    __syncthreads();
    if (!sh_act) return;            // inactive class: contributes 0
    float istd = sh_istd;
    float nm   = -sh_mu * istd;     // u = fma(x, istd, nm)

    // ---- Pass 2: KDE (data is L1/L2-hot from pass 1) ----------------------
    const float C1 = -18.033688011112042f;   // -12.5 * log2(e)
    float acc[7] = {0.f, 0.f, 0.f, 0.f, 0.f, 0.f, 0.f};

#pragma unroll 2
    for (int i = 0; i < 16; i++) {
        int g = i * 256 + t;
        float4       x  = fp4[g];
        unsigned int cv = cpu[g];
        float xs[4] = {x.x, x.y, x.z, x.w};
        float cf[4] = {(float)(cv & 255u), (float)((cv >> 8) & 255u),
                       (float)((cv >> 16) & 255u), (float)(cv >> 24)};
#pragma unroll
        for (int e = 0; e < 4; e++) {
            float u = fmaf(xs[e], istd, nm);
            float p = C1 * u;
            float q = p * u;                 // C1*u^2
#pragma unroll
            for (int k = 0; k < 7; k++) {
                float km  = (float)(k - 3);
                float arg = fmaf(p, -2.f * km, q + C1 * km * km);
                acc[k] = fmaf(cf[e], exp2_raw(arg), acc[k]);
            }
        }
    }

    __shared__ float part[4][7];
#pragma unroll
    for (int j = 0; j < 7; j++) {
        float v = acc[j];
#pragma unroll
        for (int o = 32; o > 0; o >>= 1) v += __shfl_down(v, o);
        if ((t & 63) == 0) part[wid][j] = v;
    }
    __syncthreads();

    if (t == 0) {
        // target: exp(-0.5 k^2)/Z (1/sqrt(2 pi var) cancels in normalization)
        double e[7], z = 0.0;
#pragma unroll
        for (int k = -3; k <= 3; k++) { e[k + 3] = exp(-0.5 * (double)(k * k)); z += e[k + 3]; }

        float hist[7], S = 0.f;
#pragma unroll
        for (int j = 0; j < 7; j++) {
            hist[j] = part[0][j] + part[1][j] + part[2][j] + part[3][j];
            S += hist[j];
        }
        float Ss = fmaxf(S, 1e-30f);
        float ps = 0.f;
#pragma unroll
        for (int j = 0; j < 7; j++) {
            float dd = fabsf(hist[j] / Ss - (float)(e[j] / z));
            ps += (dd < 1.f) ? 0.5f * dd * dd : (dd - 0.5f);
        }
        atomicAdd(psum, ps);        // raw partial; scaled once in K3
    }
}

// ---------------------------------------------------------------------------
// K3: finalize. A = #active classes; out = psum / (448 * A). Writes out
// absolutely (harness-poisoned d_out needs no pre-zero).
// ---------------------------------------------------------------------------
__global__ __launch_bounds__(64) void hl_final_kernel(
    const float* __restrict__ psum, const int* __restrict__ ncls,
    float* __restrict__ out)
{
    if (threadIdx.x == 0) {
        int A = 0;
#pragma unroll
        for (int i = 0; i < NCLS; i++) A += (ncls[i] >= 1000) ? 1 : 0;
        out[0] = (A > 0) ? psum[0] / (448.0f * (float)A) : 0.0f;
    }
}

// ---------------------------------------------------------------------------
extern "C" void kernel_launch(void* const* d_in, const int* in_sizes, int n_in,
                              void* d_out, int out_size, void* d_ws, size_t ws_size,
                              hipStream_t stream)
{
    const float* feature = (const float*)d_in[0];   // [1,64,128,128] fp32
    const int*   label   = (const int*)d_in[1];     // [1,1,512,512]  int32
    float*       out     = (float*)d_out;           // scalar fp32

    char* ws = (char*)d_ws;
    unsigned char* cnt  = (unsigned char*)(ws);      // 311296 B
    int*           ncls = (int*)(ws + 311296);       // 76 B
    float*         psum = (float*)(ws + 311424);     // 4 B

    hl_count_kernel<<<SRC / 256, 256, 0, stream>>>(label, cnt, psum);
    hl_fused_kernel<<<NPAIR, 256, 0, stream>>>(feature, cnt, ncls, psum);
    hl_final_kernel<<<1, 64, 0, stream>>>(psum, ncls, out);
}